// Round 12
// baseline (137.737 us; speedup 1.0000x reference)
//
#include <hip/hip_runtime.h>
#include <math.h>

// MarginDevianceLoss: N=4096, D=256, K=8, targets = i/8.
// Outputs: [loss, prec, pos_d, neg_d] fp32.
//
// R12: dispatch-count attack (6 -> 4) + zero-copy conversion:
//  - No convert kernel / no Xf buffer: GEMM blocks convert fp32->bf16 inline.
//    A-frags packed in registers; B j-slice (128 rows x K=256) staged once
//    into a single 64-KB LDS buffer (fragment-major) -> ONE barrier per
//    kernel, then 8 j-tiles of barrier-free ds_read_b128 + MFMA + epilogue.
//  - finalA+finalB fused: 16 blocks, last-block-done counter (16 atomics,
//    NOT R7's 20480), coherent partial reads via atomicAdd(p, 0).
//  - stats kernel zeroes the counter (runs 2 dispatches before finalAB).
// Dispatches: gemm1, stats, gemm2, finalAB.

#define NROWS 4096
#define DIM   256
#define KCLS  8
#define NJB   32     // j-blocks = partials per row

typedef __bf16 bf16x8 __attribute__((ext_vector_type(8)));
typedef float  f32x4  __attribute__((ext_vector_type(4)));

union U4B { uint4 u; bf16x8 v; };

// log(1+exp(z)) = max(z,0) + ln2 * log2(1 + exp2(-|z|*log2e));
// log2(1+u), u in (0,1], quartic fit (abs err <= ~4e-4).
__device__ __forceinline__ float softplus_poly(float z) {
    float u = __builtin_exp2f(-1.4426950408889634f * __builtin_fabsf(z));
    float p = u * (1.4426950f + u * (-0.6949650f + u * (0.3454302f + u * -0.0931600f)));
    return fmaf(p, 0.6931471805599453f, fmaxf(z, 0.f));
}

__device__ __forceinline__ unsigned int pack_bf2(float a, float b) {
    unsigned int ua = __float_as_uint(a);
    unsigned int ub = __float_as_uint(b);
    ua = (ua + 0x7FFFu + ((ua >> 16) & 1u)) >> 16;   // RNE
    ub = (ub + 0x7FFFu + ((ub >> 16) & 1u)) >> 16;
    return ua | (ub << 16);
}

__device__ __forceinline__ uint4 pack8(float4 a, float4 b) {
    uint4 o;
    o.x = pack_bf2(a.x, a.y);
    o.y = pack_bf2(a.z, a.w);
    o.z = pack_bf2(b.x, b.y);
    o.w = pack_bf2(b.z, b.w);
    return o;
}

// Grid (32,32). Block: 4 waves; wave w -> i-tiles {bx*8+w*2, +1} (A packed
// from fp32 X into regs, K=256). B j-slice [by*128,+128) staged fp32->bf16
// into 64-KB LDS (fragment-major) by all 256 threads, ONE barrier, then 8
// barrier-free j-tiles.
// PASS 1 (STATS=1): sum/sumsq + diag classSim -> float4 partials.
// PASS 2 (STATS=0): branchless filter + poly-softplus -> cnt/nls partials.
template<int STATS>
__global__ __launch_bounds__(256)
void gemm_pass_kernel(const float* __restrict__ X,
                      const float* __restrict__ interA,
                      const float* __restrict__ threshA,
                      float* __restrict__ outPartA,   // sumPart  / cntPart
                      float* __restrict__ outPartB,   // sqPart   / nlsPart
                      float* __restrict__ classSim)
{
    __shared__ __align__(16) unsigned short Bs[8][8][512];   // 64 KB

    const int lane = threadIdx.x & 63;
    const int wave = threadIdx.x >> 6;
    const int quad = lane >> 4;
    const int n16  = lane & 15;
    const int i0   = (blockIdx.x * 8 + wave * 2) * 16;
    const int j0   = blockIdx.y * 128;
    const bool diag = (blockIdx.x == blockIdx.y);

    // ---- stage B j-slice into LDS: 4096 16-B frag-slices, 16 per thread ----
    {
        const int t = threadIdx.x;
        #pragma unroll
        for (int p = 0; p < 16; ++p) {
            int v  = p * 256 + t;
            int jt = v >> 9;
            int kf = (v >> 6) & 7;
            int l  = v & 63;
            const float* src = X + (size_t)(j0 + jt * 16 + (l & 15)) * DIM
                                 + kf * 32 + (l >> 4) * 8;
            float4 a = *reinterpret_cast<const float4*>(src);
            float4 b = *reinterpret_cast<const float4*>(src + 4);
            *reinterpret_cast<uint4*>(&Bs[jt][kf][l * 8]) = pack8(a, b);
        }
    }

    // ---- A fragments: 2 i-tiles x 8 k-frags, packed from fp32 ----
    bf16x8 afrag[2][8];
    #pragma unroll
    for (int t = 0; t < 2; ++t) {
        const float* arow = X + (size_t)(i0 + t * 16 + n16) * DIM + quad * 8;
        #pragma unroll
        for (int kf = 0; kf < 8; ++kf) {
            float4 a = *reinterpret_cast<const float4*>(arow + kf * 32);
            float4 b = *reinterpret_cast<const float4*>(arow + kf * 32 + 4);
            U4B u; u.u = pack8(a, b);
            afrag[t][kf] = u.v;
        }
    }

    float accA[2][4] = {};       // sI / cnt
    float accB[2][4] = {};       // sqI / nls
    float c40[2][4], threshR[2][4];
    int   icls[2];
    if constexpr (!STATS) {
        #pragma unroll
        for (int t = 0; t < 2; ++t) {
            icls[t] = (i0 + t * 16 + quad * 4) >> 3;
            #pragma unroll
            for (int r = 0; r < 4; ++r) {
                int i = i0 + t * 16 + quad * 4 + r;
                c40[t][r]     = -40.f * interA[i];
                threshR[t][r] = threshA[i];
            }
        }
    }

    __syncthreads();    // the ONLY barrier

    #pragma unroll 1
    for (int jt = 0; jt < 8; ++jt) {
        bf16x8 bfr[8];
        #pragma unroll
        for (int kf = 0; kf < 8; ++kf)
            bfr[kf] = *reinterpret_cast<const bf16x8*>(&Bs[jt][kf][lane * 8]);

        f32x4 ac[2] = {{0.f, 0.f, 0.f, 0.f}, {0.f, 0.f, 0.f, 0.f}};
        #pragma unroll
        for (int kf = 0; kf < 8; ++kf) {
            ac[0] = __builtin_amdgcn_mfma_f32_16x16x32_bf16(afrag[0][kf], bfr[kf], ac[0], 0, 0, 0);
            ac[1] = __builtin_amdgcn_mfma_f32_16x16x32_bf16(afrag[1][kf], bfr[kf], ac[1], 0, 0, 0);
        }

        if constexpr (STATS) {
            #pragma unroll
            for (int t = 0; t < 2; ++t)
                #pragma unroll
                for (int r = 0; r < 4; ++r) {
                    float s = ac[t][r];
                    accA[t][r] += s;
                    accB[t][r] = fmaf(s, s, accB[t][r]);
                }
            if (diag) {                    // wave-uniform: 32/1024 blocks
                int j = j0 + jt * 16 + n16;
                #pragma unroll
                for (int t = 0; t < 2; ++t)
                    #pragma unroll
                    for (int r = 0; r < 4; ++r) {
                        int i = i0 + t * 16 + quad * 4 + r;
                        if (((i ^ j) >> 3) == 0)
                            classSim[i * KCLS + (j & 7)] = ac[t][r];
                    }
            }
        } else {
            const int jcls = (j0 + jt * 16 + n16) >> 3;
            #pragma unroll
            for (int t = 0; t < 2; ++t) {
                const bool neg = (icls[t] != jcls);
                #pragma unroll
                for (int r = 0; r < 4; ++r) {
                    float s  = ac[t][r];
                    float sp = softplus_poly(fmaf(40.f, s, c40[t][r]));
                    float m  = (neg && s > threshR[t][r]) ? 1.f : 0.f;
                    accA[t][r] += m;
                    accB[t][r] = fmaf(m, sp, accB[t][r]);
                }
            }
        }
    }

    // quad shuffle-reduce (16 lanes share rows) -> float4 partial stores
    #pragma unroll
    for (int t = 0; t < 2; ++t) {
        #pragma unroll
        for (int r = 0; r < 4; ++r) {
            #pragma unroll
            for (int m = 8; m >= 1; m >>= 1) {
                accA[t][r] += __shfl_xor(accA[t][r], m);
                accB[t][r] += __shfl_xor(accB[t][r], m);
            }
        }
        if (n16 == 0) {
            int base = blockIdx.y * NROWS + i0 + t * 16 + quad * 4;
            float4 va = {accA[t][0], accA[t][1], accA[t][2], accA[t][3]};
            float4 vb = {accB[t][0], accB[t][1], accB[t][2], accB[t][3]};
            *reinterpret_cast<float4*>(&outPartA[base]) = va;
            *reinterpret_cast<float4*>(&outPartB[base]) = vb;
        }
    }
}

// One thread per row: reduce 32 partials + classSim -> inter/thresh/posLoss/
// psum/nsum. Also zeroes the finalAB done-counter.
__global__ __launch_bounds__(256)
void stats_kernel(const float* __restrict__ sumPart,
                  const float* __restrict__ sqPart,
                  const float* __restrict__ classSim,
                  float* __restrict__ interA,
                  float* __restrict__ threshA,
                  float* __restrict__ posLossA,
                  float* __restrict__ rowPsum,
                  float* __restrict__ rowNsum,
                  unsigned int* __restrict__ counter)
{
    const int i = blockIdx.x * 256 + threadIdx.x;
    if (i == 0) *counter = 0u;
    const int self = i & 7;

    float S = 0.f, SQ = 0.f;
    #pragma unroll
    for (int b = 0; b < NJB; ++b) {
        S  += sumPart[b * NROWS + i];
        SQ += sqPart[b * NROWS + i];
    }

    float4 c0 = reinterpret_cast<const float4*>(classSim)[i * 2];
    float4 c1 = reinterpret_cast<const float4*>(classSim)[i * 2 + 1];
    float cs[KCLS] = {c0.x, c0.y, c0.z, c0.w, c1.x, c1.y, c1.z, c1.w};

    float sii = cs[self];
    float psum = 0.f, psq = 0.f, pmin = 1e30f;
    #pragma unroll
    for (int m = 0; m < KCLS; ++m) {
        if (m != self) {
            psum += cs[m];
            psq  += cs[m] * cs[m];
            pmin  = fminf(pmin, cs[m]);
        }
    }
    const float p = (float)(KCLS - 1);            // 7
    const float mneg = (float)(NROWS - KCLS);     // 4088
    float nsum = S - psum - sii;
    float nsq  = SQ - psq - sii * sii;
    float pmean = psum / p;
    float pstd  = sqrtf(fmaxf(psq / p - pmean * pmean, 0.f));
    float nmean = nsum / mneg;
    float nstd  = sqrtf(fmaxf(nsq / mneg - nmean * nmean, 0.f));
    float inter  = 0.8f * (nstd * pmean + pstd * nmean) / (pstd + nstd) + 0.1f;

    float pl = 0.f;
    #pragma unroll
    for (int m = 0; m < KCLS; ++m) {
        if (m != self) pl += softplus_poly(-10.f * (cs[m] - inter));
    }
    pl *= 0.2f / p;

    interA[i]   = inter;
    threshA[i]  = pmin - 0.05f;
    posLossA[i] = pl;
    rowPsum[i]  = psum;
    rowNsum[i]  = nsum;
}

// 16 blocks x 256 threads; thread -> one row. Reduce cnt/nls partials ->
// rowLoss/rowInv, block-reduce 4 sums, last block combines -> out.
__global__ __launch_bounds__(256)
void finalAB_kernel(const float* __restrict__ cntPart,
                    const float* __restrict__ nlsPart,
                    const float* __restrict__ posLossA,
                    const float* __restrict__ rowPsum,
                    const float* __restrict__ rowNsum,
                    float* __restrict__ blkPart,      // 16*4 floats
                    unsigned int* __restrict__ counter,
                    float* __restrict__ out)
{
    const int t = threadIdx.x;
    const int i = blockIdx.x * 256 + t;

    float c = 0.f, n = 0.f;
    #pragma unroll
    for (int b = 0; b < NJB; ++b) {
        c += cntPart[b * NROWS + i];
        n += nlsPart[b * NROWS + i];
    }
    float loss = (c > 0.f) ? (posLossA[i] + 0.05f * n / c) : 0.f;
    float inv  = (c > 0.f) ? 0.f : 1.f;
    float pd   = rowPsum[i];
    float nd   = rowNsum[i];

    #pragma unroll
    for (int off = 32; off > 0; off >>= 1) {
        loss += __shfl_down(loss, off);
        inv  += __shfl_down(inv, off);
        pd   += __shfl_down(pd, off);
        nd   += __shfl_down(nd, off);
    }
    __shared__ float sl[4], si[4], sp[4], sq[4];
    int w = t >> 6;
    if ((t & 63) == 0) { sl[w] = loss; si[w] = inv; sp[w] = pd; sq[w] = nd; }
    __syncthreads();
    if (t == 0) {
        blkPart[blockIdx.x * 4 + 0] = sl[0] + sl[1] + sl[2] + sl[3];
        blkPart[blockIdx.x * 4 + 1] = si[0] + si[1] + si[2] + si[3];
        blkPart[blockIdx.x * 4 + 2] = sp[0] + sp[1] + sp[2] + sp[3];
        blkPart[blockIdx.x * 4 + 3] = sq[0] + sq[1] + sq[2] + sq[3];
        __threadfence();
        unsigned int old = atomicAdd(counter, 1u);
        sl[0] = (old == 15u) ? 1.f : 0.f;       // reuse LDS as flag
    }
    __syncthreads();
    if (sl[0] != 0.f && t < 64) {
        // last block: coherent read of all 64 partials (distinct addresses)
        float v = atomicAdd(&blkPart[t], 0.f);
        #pragma unroll
        for (int off = 4; off < 64; off <<= 1) v += __shfl_xor(v, off);
        // lanes 0..3 now hold totals: loss, inv, psum, nsum
        if (t == 0) out[0] = v / (float)NROWS;
        if (t == 1) out[1] = v / (float)NROWS;
        if (t == 2) out[2] = v / ((float)NROWS * (float)(KCLS - 1));
        if (t == 3) out[3] = v / ((float)NROWS * (float)(NROWS - KCLS));
    }
}

extern "C" void kernel_launch(void* const* d_in, const int* in_sizes, int n_in,
                              void* d_out, int out_size, void* d_ws, size_t ws_size,
                              hipStream_t stream)
{
    const float* X = (const float*)d_in[0];

    float* ws       = (float*)d_ws;
    float* sumPart  = ws;                                   // 32*4096
    float* sqPart   = sumPart + NJB * NROWS;                // 32*4096
    float* cntPart  = sqPart  + NJB * NROWS;                // 32*4096
    float* nlsPart  = cntPart + NJB * NROWS;                // 32*4096
    float* classSim = nlsPart + NJB * NROWS;                // 4096*8
    float* interA   = classSim + NROWS * KCLS;              // 4096
    float* threshA  = interA  + NROWS;
    float* posLossA = threshA + NROWS;
    float* rowPsum  = posLossA + NROWS;
    float* rowNsum  = rowPsum + NROWS;
    float* blkPart  = rowNsum + NROWS;                      // 64
    unsigned int* counter = (unsigned int*)(blkPart + 64);  // 1
    // total ws use: ~2.4 MB; counter zeroed by stats (2 dispatches before use)

    dim3 grid(32, 32);
    gemm_pass_kernel<1><<<grid, 256, 0, stream>>>(X, nullptr, nullptr,
                                                  sumPart, sqPart, classSim);

    stats_kernel<<<NROWS / 256, 256, 0, stream>>>(sumPart, sqPart, classSim,
                                                  interA, threshA, posLossA,
                                                  rowPsum, rowNsum, counter);

    gemm_pass_kernel<0><<<grid, 256, 0, stream>>>(X, interA, threshA,
                                                  cntPart, nlsPart, nullptr);

    finalAB_kernel<<<16, 256, 0, stream>>>(cntPart, nlsPart, posLossA,
                                           rowPsum, rowNsum, blkPart, counter,
                                           (float*)d_out);
}